// Round 9
// baseline (269.494 us; speedup 1.0000x reference)
//
#include <hip/hip_runtime.h>
#include <math.h>

// ---------------------------------------------------------------------------
// MinGRU, 2 layers. B=8, S=4096, D=H=512.
// Round 13: r12 (best: 264.1) + ONE change: pass3 stages its 64 KB gh chunk
// into LDS via global_load_lds (16 asyncs/thread, pure DMA) and replays from
// LDS. Decouples HBM streaming from the serial recurrence: the old replay
// interleaved dependent loads with stores on the shared vmcnt counter ->
// shallow prefetch, ~2 TB/s. Now: DMA issues back-to-back (max queue depth),
// the two-level prefix (L2-resident) overlaps the DMA, one barrier drains,
// replay reads LDS (lgkmcnt, independent of store vmcnt).
// gemm/cast3 untouched (gemm = proven local optimum: BK=64,
// stage->sync->compute->sync; r7/r8 pipeline variants both regressed).
// 5 dispatches.
// ---------------------------------------------------------------------------

typedef unsigned short u16;
typedef __attribute__((ext_vector_type(8))) short short8;   // 8 bf16 = 4 VGPR
typedef __attribute__((ext_vector_type(4))) float f32x4;

__device__ __forceinline__ u16 f2bf(float f) {
    unsigned int u = __float_as_uint(f);
    return (u16)((u + 0x7fffu + ((u >> 16) & 1u)) >> 16);   // RNE
}
__device__ __forceinline__ float bf2f(u16 u) {
    return __uint_as_float(((unsigned int)u) << 16);
}
__device__ __forceinline__ void async16(const void* g, void* l) {
    __builtin_amdgcn_global_load_lds(
        (const __attribute__((address_space(1))) unsigned int*)g,
        (__attribute__((address_space(3))) unsigned int*)l, 16, 0, 0);
}
__device__ __forceinline__ float fastrcp(float x) { return __builtin_amdgcn_rcpf(x); }

// c = sigmoid(-gate); v = sigmoid(gate) * g(hid). 2 exp + 2 v_rcp.
__device__ __forceinline__ void coeff_val(float gate, float hid, float& c, float& v)
{
    float cc = fastrcp(1.0f + __expf(gate));      // sigmoid(-gate)
    float gp = hid + 0.5f;                        // hid >= 0 branch
    float gn = fastrcp(1.0f + __expf(-hid));      // sigmoid(hid), hid < 0 branch
    float g  = (hid >= 0.0f) ? gp : gn;
    c = cc;
    v = (1.0f - cc) * g;
}

// ---------------------------------------------------------------------------
// Fused cast: x (nx4 float4s) then w0, w1 (nw4 float4s each), one flat grid.
// ---------------------------------------------------------------------------
__global__ __launch_bounds__(256) void cast3(
    const float* __restrict__ x,  u16* __restrict__ xb,  int nx4,
    const float* __restrict__ w0, u16* __restrict__ w0b,
    const float* __restrict__ w1, u16* __restrict__ w1b, int nw4)
{
    int i = blockIdx.x * 256 + threadIdx.x;
    const float* src; u16* dst; int idx;
    if (i < nx4)                { src = x;  dst = xb;  idx = i; }
    else if (i < nx4 + nw4)     { src = w0; dst = w0b; idx = i - nx4; }
    else if (i < nx4 + 2 * nw4) { src = w1; dst = w1b; idx = i - nx4 - nw4; }
    else return;
    float4 v = ((const float4*)src)[idx];
    ushort4 o = make_ushort4(f2bf(v.x), f2bf(v.y), f2bf(v.z), f2bf(v.w));
    ((ushort4*)dst)[idx] = o;
}

// ---------------------------------------------------------------------------
// gemm_fused: C = A(128 rows) . Wperm^T; register-direct epilogue computes
// (c,v), packs bf16 pairs into an LDS tile for the coalesced gh store and the
// fused pass1 (4 chunks of 32 rows + block summary). Grid (8, M/128), XCD-swz.
// W tile row r: ch(r) = (r&31) + ((r&64)>>1), is_hid = (r>>5)&1,
//               W row = bn*64 + ch + is_hid*512.
// => wave half w1: frags j=0,1 gate of ch w1*32+j*16+fm; j=2,3 hidden (same).
// (Round-5 K-loop: BK=64, 128-B rows, ^(row&7) granule swizzle,
//  stage -> sync -> compute -> sync, 8 K-steps.)
// ---------------------------------------------------------------------------
#define TST 144   // epilogue (c,v)-tile row stride in u16 (72 dwords)

__global__ __launch_bounds__(256) void gemm_fused(
    const u16* __restrict__ A, const u16* __restrict__ W,
    const float* __restrict__ bias, u16* __restrict__ gh,
    float* __restrict__ cA, float* __restrict__ cV,
    float* __restrict__ cBA, float* __restrict__ cBV, int K)
{
    __shared__ __align__(16) u16 lds[128 * TST];   // 36864 B; K-loop uses first 32 KB
    __shared__ float2 csum[4][64];                 // [chunk][ch] summaries (2 KB)

    u16* Asm = lds;           // 128 x 64 bf16 = 16 KB
    u16* Wsm = lds + 8192;    // 16 KB

    const int tid  = threadIdx.x;
    // XCD-aware swizzle: nwg = 2048 = 8 * 256 (divisible by 8 -> bijective).
    const int d    = blockIdx.y * 8 + blockIdx.x;
    const int cpx  = (int)(gridDim.x * gridDim.y) >> 3;
    const int t0   = (d & 7) * cpx + (d >> 3);
    const int bn   = t0 & 7;                // channel block [bn*64, bn*64+64)
    const int bm   = t0 >> 3;               // row block
    const int lane = tid & 63;
    const int wave = tid >> 6;
    const int wm   = (wave >> 1) * 64;
    const int wn   = (wave & 1) * 64;
    const int w1   = wave & 1;
    const int fm   = lane & 15;
    const int kb   = lane >> 4;

    // staging: 4 granules (16 B)/thread/operand; row = 128 B = 8 granules.
    // Pre-swizzled global source, linear LDS dest (global_load_lds rule).
    const u16* Ap[4]; const u16* Wp[4]; char* lA[4]; char* lW[4];
    #pragma unroll
    for (int t = 0; t < 4; ++t) {
        const int gt = tid + 256 * t;
        const int r  = gt >> 3;
        const int q  = (gt & 7) ^ (r & 7);
        Ap[t] = A + (size_t)(bm * 128 + r) * 512 + q * 8;
        const int wr = bn * 64 + (r & 31) + ((r & 64) >> 1) + ((r & 32) ? 512 : 0);
        Wp[t] = W + (size_t)wr * 512 + q * 8;
        lA[t] = (char*)Asm + gt * 16;
        lW[t] = (char*)Wsm + gt * 16;
    }

    // fragment read offsets (bytes), ks=0; ks=1 is ^64 (granule q ^ 4)
    int offA[4], offB[4];
    #pragma unroll
    for (int i = 0; i < 4; ++i) {
        const int rowA = wm + i * 16 + fm;
        offA[i] = rowA * 128 + ((kb ^ (rowA & 7)) * 16);
        const int rowB = wn + i * 16 + fm;
        offB[i] = rowB * 128 + ((kb ^ (rowB & 7)) * 16);
    }

    f32x4 acc[4][4];
    #pragma unroll
    for (int i = 0; i < 4; ++i)
        #pragma unroll
        for (int j = 0; j < 4; ++j)
            acc[i][j] = (f32x4){0.f, 0.f, 0.f, 0.f};

    const char* AsB = (const char*)Asm;
    const char* WsB = (const char*)Wsm;

    for (int kt = 0; kt < K; kt += 64) {
        #pragma unroll
        for (int t = 0; t < 4; ++t) { async16(Ap[t], lA[t]); async16(Wp[t], lW[t]); }
        __syncthreads();
        #pragma unroll
        for (int ks = 0; ks < 2; ++ks) {
            const int xo = ks << 6;
            short8 a[4], b[4];
            #pragma unroll
            for (int i = 0; i < 4; ++i) a[i] = *(const short8*)(AsB + (offA[i] ^ xo));
            #pragma unroll
            for (int j = 0; j < 4; ++j) b[j] = *(const short8*)(WsB + (offB[j] ^ xo));
            #pragma unroll
            for (int i = 0; i < 4; ++i)
                #pragma unroll
                for (int j = 0; j < 4; ++j)
                    acc[i][j] = __builtin_amdgcn_mfma_f32_16x16x32_bf16(
                        a[i], b[j], acc[i][j], 0, 0, 0);
        }
        __syncthreads();
        #pragma unroll
        for (int t = 0; t < 4; ++t) { Ap[t] += 64; Wp[t] += 64; }
    }

    // ---- epilogue: coeff_val on f32 accumulators, pack (c,v) bf16 into LDS ----
    float bg[2], bh[2];
    #pragma unroll
    for (int jj = 0; jj < 2; ++jj) {
        const int chl = w1 * 32 + jj * 16 + fm;
        bg[jj] = bias[bn * 64 + chl];
        bh[jj] = bias[512 + bn * 64 + chl];
    }
    unsigned int* ldsw = (unsigned int*)lds;   // 72 dwords per row (TST/2)
    #pragma unroll
    for (int i = 0; i < 4; ++i)
        #pragma unroll
        for (int jj = 0; jj < 2; ++jj) {
            const int chl = w1 * 32 + jj * 16 + fm;
            const f32x4 g4 = acc[i][jj];        // gate fragment
            const f32x4 h4 = acc[i][jj + 2];    // hidden fragment, same channels
            #pragma unroll
            for (int r = 0; r < 4; ++r) {
                const int row = wm + i * 16 + kb * 4 + r;
                float c, v;
                coeff_val(g4[r] + bg[jj], h4[r] + bh[jj], c, v);
                ldsw[row * 72 + chl] = (unsigned int)f2bf(c)
                                     | ((unsigned int)f2bf(v) << 16);
            }
        }
    __syncthreads();

    // ---- coalesced gh store: 128 u16 of interleaved (c,v) per row ----
    #pragma unroll
    for (int it = 0; it < 8; ++it) {
        const int row = it * 16 + (tid >> 4);
        const int sc  = (tid & 15) * 8;
        short8 vv = *(const short8*)&lds[row * TST + sc];
        *(short8*)&gh[(size_t)(bm * 128 + row) * 1024 + bn * 128 + sc] = vv;
    }

    // ---- fused pass1: 4 chunks of 32 rows (rounded c,v so carry/replay stay
    //      consistent with pass3), plus 128-row block summary via LDS ----
    const int ch = tid & 63;
    const int ck = tid >> 6;              // 0..3
    float Aa = 1.f, Vv = 0.f;
    #pragma unroll 4
    for (int s = 0; s < 32; ++s) {
        const unsigned int p = ldsw[(ck * 32 + s) * 72 + ch];
        const float c = bf2f((u16)p);
        const float v = bf2f((u16)(p >> 16));
        Aa *= c;
        Vv = fmaf(c, Vv, v);
    }
    const int bb  = bm >> 5;                 // 32 row-blocks per batch
    const int ckg = (bm & 31) * 4 + ck;      // global chunk in [0,128)
    const size_t idx = ((size_t)(bb * 128 + ckg)) * 512 + bn * 64 + ch;
    cA[idx] = Aa;
    cV[idx] = Vv;
    csum[ck][ch] = make_float2(Aa, Vv);
    __syncthreads();
    if (ck == 0) {
        float Ab = 1.f, Vb = 0.f;
        #pragma unroll
        for (int j = 0; j < 4; ++j) {
            float2 s = csum[j][ch];
            Ab = s.x * Ab;
            Vb = fmaf(s.x, Vb, s.y);
        }
        const size_t bidx = ((size_t)(bb * 32 + (bm & 31))) * 512 + bn * 64 + ch;
        cBA[bidx] = Ab;
        cBV[bidx] = Vb;
    }
}

// ---------------------------------------------------------------------------
// pass3 (with fused two-level pass2): issue a 64 KB global_load_lds DMA of
// this block's gh chunk, compute the two-level prefix (coarse block
// summaries [0, ck/4) + fine chunks, all L2-resident) while the DMA is in
// flight, one barrier, then replay from LDS.
// ---------------------------------------------------------------------------
template <bool OUT_BF16>
__global__ __launch_bounds__(256) void scan_pass3(
    const u16* __restrict__ gh,
    const float* __restrict__ cA, const float* __restrict__ cV,
    const float* __restrict__ cBA, const float* __restrict__ cBV,
    void* __restrict__ outv, float* __restrict__ nh,
    int S, int Lc, int Nc)
{
    __shared__ __align__(16) u16 chunk[32 * 1024];   // 64 KB (Lc=32 rows x 2048 B)
    const int tid = threadIdx.x;
    const int b   = blockIdx.x / Nc;
    const int ck  = blockIdx.x % Nc;
    const int blk = ck >> 2;             // 128-row block index in [0,32)

    // ---- issue chunk DMA: 16 x 16 B per thread, linear LDS dest ----
    {
        const u16* s0 = gh + (size_t)(b * S + ck * Lc) * 1024 + tid * 8;
        char* d0 = (char*)chunk + tid * 16;
        #pragma unroll
        for (int i = 0; i < 16; ++i) {
            async16(s0, d0);
            s0 += 2048;      // 256 threads * 8 u16
            d0 += 4096;      // 256 threads * 16 B
        }
    }

    // ---- two-level prefix (overlaps the DMA) ----
    float h0 = 0.5f, h1 = 0.5f;
    #pragma unroll 4
    for (int j = 0; j < blk; ++j) {
        const size_t idx = (size_t)(b * 32 + j) * 512 + 2 * tid;
        float2 a = *(const float2*)(cBA + idx);
        float2 v = *(const float2*)(cBV + idx);
        h0 = fmaf(a.x, h0, v.x);
        h1 = fmaf(a.y, h1, v.y);
    }
    for (int j = blk * 4; j < ck; ++j) {
        const size_t idx = (size_t)(b * Nc + j) * 512 + 2 * tid;
        float2 a = *(const float2*)(cA + idx);
        float2 v = *(const float2*)(cV + idx);
        h0 = fmaf(a.x, h0, v.x);
        h1 = fmaf(a.y, h1, v.y);
    }

    __syncthreads();   // per-wave vmcnt drain -> whole 64 KB chunk visible

    // ---- replay from LDS ----
    const size_t obase = (size_t)(b * S + ck * Lc) * 512 + 2 * tid;
    #pragma unroll 4
    for (int s = 0; s < Lc; ++s) {
        ushort4 q = *(const ushort4*)(chunk + s * 1024 + 4 * tid);
        h0 = fmaf(bf2f(q.x), h0, bf2f(q.y));
        h1 = fmaf(bf2f(q.z), h1, bf2f(q.w));
        if (OUT_BF16) {
            ushort2 o = make_ushort2(f2bf(h0), f2bf(h1));
            *(ushort2*)((u16*)outv + obase + (size_t)s * 512) = o;
        } else {
            *(float2*)((float*)outv + obase + (size_t)s * 512) = make_float2(h0, h1);
        }
    }
    if (ck == Nc - 1)
        *(float2*)(nh + (size_t)b * 512 + 2 * tid) = make_float2(h0, h1);
}

// ---------------------------------------------------------------------------
extern "C" void kernel_launch(void* const* d_in, const int* in_sizes, int n_in,
                              void* d_out, int out_size, void* d_ws, size_t ws_size,
                              hipStream_t stream)
{
    const float* x  = (const float*)d_in[0];
    const float* w0 = (const float*)d_in[1];
    const float* b0 = (const float*)d_in[2];
    const float* w1 = (const float*)d_in[3];
    const float* b1 = (const float*)d_in[4];
    float* out = (float*)d_out;

    const int B = 8, S = 4096, K = 512;
    const int M = B * S;             // 32768
    const int Lc = 32, Nc = S / Lc;  // 128 chunks of 32

    // workspace (bf16 elems): gh M*1024, xb M*512 (h0b aliases xb: xb is dead
    // after gemm0, which completes before pass3-L0 writes h0b), w0b/w1b.
    u16* gh  = (u16*)d_ws;
    u16* xb  = gh  + (size_t)M * 1024;
    u16* h0b = xb;                       // alias (stream-ordered safe)
    u16* w0b = xb  + (size_t)M * 512;
    u16* w1b = w0b + (size_t)1024 * 512;
    float* cA  = (float*)(w1b + (size_t)1024 * 512);
    float* cV  = cA  + (size_t)B * Nc * 512;
    float* cBA = cV  + (size_t)B * Nc * 512;
    float* cBV = cBA + (size_t)B * 32 * 512;

    float* nh0 = out + (size_t)M * 512;
    float* nh1 = nh0 + (size_t)B * 512;

    dim3 blk(256);
    dim3 ggrid(8, M / 128);          // 8 channel-blocks x 256 row-blocks
    dim3 sgrid(B * Nc);              // 1024

    const int nx4 = M * K / 4;           // 4,194,304
    const int nw4 = 1024 * K / 4;        // 131,072
    cast3<<<dim3((nx4 + 2 * nw4 + 255) / 256), blk, 0, stream>>>(
        x, xb, nx4, w0, w0b, w1, w1b, nw4);

    // ---- layer 0 ----
    gemm_fused<<<ggrid, blk, 0, stream>>>(xb, w0b, b0, gh, cA, cV, cBA, cBV, K);
    scan_pass3<true><<<sgrid, blk, 0, stream>>>(
        gh, cA, cV, cBA, cBV, h0b, nh0, S, Lc, Nc);

    // ---- layer 1 ----
    gemm_fused<<<ggrid, blk, 0, stream>>>(h0b, w1b, b1, gh, cA, cV, cBA, cBV, K);
    scan_pass3<false><<<sgrid, blk, 0, stream>>>(
        gh, cA, cV, cBA, cBV, out, nh1, S, Lc, Nc);
}

// Round 10
// 259.126 us; speedup vs baseline: 1.0400x; 1.0400x over previous
//
#include <hip/hip_runtime.h>
#include <math.h>

// ---------------------------------------------------------------------------
// MinGRU, 2 layers. B=8, S=4096, D=H=512.
// Round 14: r12 (best: 264.1; r13's pass3-LDS reverted — 64KB/block halved
// occupancy) + two VALU-path micro-opts:
// 1) v_cvt_pk_bf16_f32 (asm; no builtin on gfx950) replaces the ~9-instr
//    manual RNE f2bf+pack per (c,v) pair in the gemm epilogue (32/thread,
//    VALUBusy 56% -> biggest single VALU chunk), in cast3, and in pass3's
//    bf16 store. Same RNE rounding; packed value used consistently.
// 2) pass3 replay: 4 bursts of {8 loads -> regs, then 8 compute+store}
//    decouples load-waits from store retirement on the shared vmcnt counter
//    (r13's goal) without the LDS occupancy cost; Lc/Nc compile-time.
// gemm K-loop untouched (proven local optimum). 5 dispatches.
// ---------------------------------------------------------------------------

typedef unsigned short u16;
typedef __attribute__((ext_vector_type(8))) short short8;   // 8 bf16 = 4 VGPR
typedef __attribute__((ext_vector_type(4))) float f32x4;

__device__ __forceinline__ u16 f2bf(float f) {
    unsigned int u = __float_as_uint(f);
    return (u16)((u + 0x7fffu + ((u >> 16) & 1u)) >> 16);   // RNE
}
__device__ __forceinline__ float bf2f(u16 u) {
    return __uint_as_float(((unsigned int)u) << 16);
}
// packed bf16 pair: low16 = bf16(lo), high16 = bf16(hi); RNE (matches f2bf)
__device__ __forceinline__ unsigned int pk_bf16(float lo, float hi) {
    unsigned int r;
    asm("v_cvt_pk_bf16_f32 %0, %1, %2" : "=v"(r) : "v"(lo), "v"(hi));
    return r;
}
__device__ __forceinline__ void async16(const void* g, void* l) {
    __builtin_amdgcn_global_load_lds(
        (const __attribute__((address_space(1))) unsigned int*)g,
        (__attribute__((address_space(3))) unsigned int*)l, 16, 0, 0);
}
__device__ __forceinline__ float fastrcp(float x) { return __builtin_amdgcn_rcpf(x); }

// c = sigmoid(-gate); v = sigmoid(gate) * g(hid). 2 exp + 2 v_rcp.
__device__ __forceinline__ void coeff_val(float gate, float hid, float& c, float& v)
{
    float cc = fastrcp(1.0f + __expf(gate));      // sigmoid(-gate)
    float gp = hid + 0.5f;                        // hid >= 0 branch
    float gn = fastrcp(1.0f + __expf(-hid));      // sigmoid(hid), hid < 0 branch
    float g  = (hid >= 0.0f) ? gp : gn;
    c = cc;
    v = (1.0f - cc) * g;
}

// ---------------------------------------------------------------------------
// Fused cast: x (nx4 float4s) then w0, w1 (nw4 float4s each), one flat grid.
// ---------------------------------------------------------------------------
__global__ __launch_bounds__(256) void cast3(
    const float* __restrict__ x,  u16* __restrict__ xb,  int nx4,
    const float* __restrict__ w0, u16* __restrict__ w0b,
    const float* __restrict__ w1, u16* __restrict__ w1b, int nw4)
{
    int i = blockIdx.x * 256 + threadIdx.x;
    const float* src; u16* dst; int idx;
    if (i < nx4)                { src = x;  dst = xb;  idx = i; }
    else if (i < nx4 + nw4)     { src = w0; dst = w0b; idx = i - nx4; }
    else if (i < nx4 + 2 * nw4) { src = w1; dst = w1b; idx = i - nx4 - nw4; }
    else return;
    float4 v = ((const float4*)src)[idx];
    uint2 o = make_uint2(pk_bf16(v.x, v.y), pk_bf16(v.z, v.w));
    ((uint2*)dst)[idx] = o;
}

// ---------------------------------------------------------------------------
// gemm_fused: C = A(128 rows) . Wperm^T; register-direct epilogue computes
// (c,v), packs bf16 pairs into an LDS tile for the coalesced gh store and the
// fused pass1 (4 chunks of 32 rows + block summary). Grid (8, M/128), XCD-swz.
// W tile row r: ch(r) = (r&31) + ((r&64)>>1), is_hid = (r>>5)&1,
//               W row = bn*64 + ch + is_hid*512.
// => wave half w1: frags j=0,1 gate of ch w1*32+j*16+fm; j=2,3 hidden (same).
// (Round-5 K-loop: BK=64, 128-B rows, ^(row&7) granule swizzle,
//  stage -> sync -> compute -> sync, 8 K-steps.)
// ---------------------------------------------------------------------------
#define TST 144   // epilogue (c,v)-tile row stride in u16 (72 dwords)

__global__ __launch_bounds__(256) void gemm_fused(
    const u16* __restrict__ A, const u16* __restrict__ W,
    const float* __restrict__ bias, u16* __restrict__ gh,
    float* __restrict__ cA, float* __restrict__ cV,
    float* __restrict__ cBA, float* __restrict__ cBV, int K)
{
    __shared__ __align__(16) u16 lds[128 * TST];   // 36864 B; K-loop uses first 32 KB
    __shared__ float2 csum[4][64];                 // [chunk][ch] summaries (2 KB)

    u16* Asm = lds;           // 128 x 64 bf16 = 16 KB
    u16* Wsm = lds + 8192;    // 16 KB

    const int tid  = threadIdx.x;
    // XCD-aware swizzle: nwg = 2048 = 8 * 256 (divisible by 8 -> bijective).
    const int d    = blockIdx.y * 8 + blockIdx.x;
    const int cpx  = (int)(gridDim.x * gridDim.y) >> 3;
    const int t0   = (d & 7) * cpx + (d >> 3);
    const int bn   = t0 & 7;                // channel block [bn*64, bn*64+64)
    const int bm   = t0 >> 3;               // row block
    const int lane = tid & 63;
    const int wave = tid >> 6;
    const int wm   = (wave >> 1) * 64;
    const int wn   = (wave & 1) * 64;
    const int w1   = wave & 1;
    const int fm   = lane & 15;
    const int kb   = lane >> 4;

    // staging: 4 granules (16 B)/thread/operand; row = 128 B = 8 granules.
    // Pre-swizzled global source, linear LDS dest (global_load_lds rule).
    const u16* Ap[4]; const u16* Wp[4]; char* lA[4]; char* lW[4];
    #pragma unroll
    for (int t = 0; t < 4; ++t) {
        const int gt = tid + 256 * t;
        const int r  = gt >> 3;
        const int q  = (gt & 7) ^ (r & 7);
        Ap[t] = A + (size_t)(bm * 128 + r) * 512 + q * 8;
        const int wr = bn * 64 + (r & 31) + ((r & 64) >> 1) + ((r & 32) ? 512 : 0);
        Wp[t] = W + (size_t)wr * 512 + q * 8;
        lA[t] = (char*)Asm + gt * 16;
        lW[t] = (char*)Wsm + gt * 16;
    }

    // fragment read offsets (bytes), ks=0; ks=1 is ^64 (granule q ^ 4)
    int offA[4], offB[4];
    #pragma unroll
    for (int i = 0; i < 4; ++i) {
        const int rowA = wm + i * 16 + fm;
        offA[i] = rowA * 128 + ((kb ^ (rowA & 7)) * 16);
        const int rowB = wn + i * 16 + fm;
        offB[i] = rowB * 128 + ((kb ^ (rowB & 7)) * 16);
    }

    f32x4 acc[4][4];
    #pragma unroll
    for (int i = 0; i < 4; ++i)
        #pragma unroll
        for (int j = 0; j < 4; ++j)
            acc[i][j] = (f32x4){0.f, 0.f, 0.f, 0.f};

    const char* AsB = (const char*)Asm;
    const char* WsB = (const char*)Wsm;

    for (int kt = 0; kt < K; kt += 64) {
        #pragma unroll
        for (int t = 0; t < 4; ++t) { async16(Ap[t], lA[t]); async16(Wp[t], lW[t]); }
        __syncthreads();
        #pragma unroll
        for (int ks = 0; ks < 2; ++ks) {
            const int xo = ks << 6;
            short8 a[4], b[4];
            #pragma unroll
            for (int i = 0; i < 4; ++i) a[i] = *(const short8*)(AsB + (offA[i] ^ xo));
            #pragma unroll
            for (int j = 0; j < 4; ++j) b[j] = *(const short8*)(WsB + (offB[j] ^ xo));
            #pragma unroll
            for (int i = 0; i < 4; ++i)
                #pragma unroll
                for (int j = 0; j < 4; ++j)
                    acc[i][j] = __builtin_amdgcn_mfma_f32_16x16x32_bf16(
                        a[i], b[j], acc[i][j], 0, 0, 0);
        }
        __syncthreads();
        #pragma unroll
        for (int t = 0; t < 4; ++t) { Ap[t] += 64; Wp[t] += 64; }
    }

    // ---- epilogue: coeff_val on f32 accumulators, cvt_pk (c,v) into LDS ----
    float bg[2], bh[2];
    #pragma unroll
    for (int jj = 0; jj < 2; ++jj) {
        const int chl = w1 * 32 + jj * 16 + fm;
        bg[jj] = bias[bn * 64 + chl];
        bh[jj] = bias[512 + bn * 64 + chl];
    }
    unsigned int* ldsw = (unsigned int*)lds;   // 72 dwords per row (TST/2)
    #pragma unroll
    for (int i = 0; i < 4; ++i)
        #pragma unroll
        for (int jj = 0; jj < 2; ++jj) {
            const int chl = w1 * 32 + jj * 16 + fm;
            const f32x4 g4 = acc[i][jj];        // gate fragment
            const f32x4 h4 = acc[i][jj + 2];    // hidden fragment, same channels
            #pragma unroll
            for (int r = 0; r < 4; ++r) {
                const int row = wm + i * 16 + kb * 4 + r;
                float c, v;
                coeff_val(g4[r] + bg[jj], h4[r] + bh[jj], c, v);
                ldsw[row * 72 + chl] = pk_bf16(c, v);
            }
        }
    __syncthreads();

    // ---- coalesced gh store: 128 u16 of interleaved (c,v) per row ----
    #pragma unroll
    for (int it = 0; it < 8; ++it) {
        const int row = it * 16 + (tid >> 4);
        const int sc  = (tid & 15) * 8;
        short8 vv = *(const short8*)&lds[row * TST + sc];
        *(short8*)&gh[(size_t)(bm * 128 + row) * 1024 + bn * 128 + sc] = vv;
    }

    // ---- fused pass1: 4 chunks of 32 rows (rounded c,v so carry/replay stay
    //      consistent with pass3), plus 128-row block summary via LDS ----
    const int ch = tid & 63;
    const int ck = tid >> 6;              // 0..3
    float Aa = 1.f, Vv = 0.f;
    #pragma unroll 4
    for (int s = 0; s < 32; ++s) {
        const unsigned int p = ldsw[(ck * 32 + s) * 72 + ch];
        const float c = bf2f((u16)p);
        const float v = bf2f((u16)(p >> 16));
        Aa *= c;
        Vv = fmaf(c, Vv, v);
    }
    const int bb  = bm >> 5;                 // 32 row-blocks per batch
    const int ckg = (bm & 31) * 4 + ck;      // global chunk in [0,128)
    const size_t idx = ((size_t)(bb * 128 + ckg)) * 512 + bn * 64 + ch;
    cA[idx] = Aa;
    cV[idx] = Vv;
    csum[ck][ch] = make_float2(Aa, Vv);
    __syncthreads();
    if (ck == 0) {
        float Ab = 1.f, Vb = 0.f;
        #pragma unroll
        for (int j = 0; j < 4; ++j) {
            float2 s = csum[j][ch];
            Ab = s.x * Ab;
            Vb = fmaf(s.x, Vb, s.y);
        }
        const size_t bidx = ((size_t)(bb * 32 + (bm & 31))) * 512 + bn * 64 + ch;
        cBA[bidx] = Ab;
        cBV[bidx] = Vb;
    }
}

// ---------------------------------------------------------------------------
// pass3 (with fused two-level pass2): carry = coarse fold over 128-row block
// summaries [0, ck/4) (<=31 iters) + fine fold over 32-row chunks (<=3),
// all L2-resident; then replay in 4 bursts of {8 loads -> regs, 8 fma+store}
// so load-waits don't queue behind store retirement on the shared vmcnt.
// ---------------------------------------------------------------------------
template <bool OUT_BF16>
__global__ __launch_bounds__(256) void scan_pass3(
    const u16* __restrict__ gh,
    const float* __restrict__ cA, const float* __restrict__ cV,
    const float* __restrict__ cBA, const float* __restrict__ cBV,
    void* __restrict__ outv, float* __restrict__ nh)
{
    constexpr int S = 4096, LC = 32, NC = 128;
    const int tid = threadIdx.x;
    const int b   = blockIdx.x >> 7;     // / NC
    const int ck  = blockIdx.x & (NC - 1);
    const int blk = ck >> 2;             // 128-row block index in [0,32)

    float h0 = 0.5f, h1 = 0.5f;
    // ---- coarse prefix: block summaries [0, blk) ----
    #pragma unroll 4
    for (int j = 0; j < blk; ++j) {
        const size_t idx = (size_t)(b * 32 + j) * 512 + 2 * tid;
        float2 a = *(const float2*)(cBA + idx);
        float2 v = *(const float2*)(cBV + idx);
        h0 = fmaf(a.x, h0, v.x);
        h1 = fmaf(a.y, h1, v.y);
    }
    // ---- fine prefix: chunks [blk*4, ck) ----
    for (int j = blk * 4; j < ck; ++j) {
        const size_t idx = (size_t)(b * NC + j) * 512 + 2 * tid;
        float2 a = *(const float2*)(cA + idx);
        float2 v = *(const float2*)(cV + idx);
        h0 = fmaf(a.x, h0, v.x);
        h1 = fmaf(a.y, h1, v.y);
    }

    // ---- replay this chunk: 4 x {burst-load 8, compute+store 8} ----
    const u16* base = gh + (size_t)(b * S + ck * LC) * 1024 + 4 * tid;
    const size_t obase = (size_t)(b * S + ck * LC) * 512 + 2 * tid;
    #pragma unroll
    for (int g = 0; g < 4; ++g) {
        ushort4 q[8];
        #pragma unroll
        for (int s = 0; s < 8; ++s)
            q[s] = *(const ushort4*)(base + (size_t)(g * 8 + s) * 1024);
        #pragma unroll
        for (int s = 0; s < 8; ++s) {
            h0 = fmaf(bf2f(q[s].x), h0, bf2f(q[s].y));
            h1 = fmaf(bf2f(q[s].z), h1, bf2f(q[s].w));
            const size_t so = obase + (size_t)(g * 8 + s) * 512;
            if (OUT_BF16) {
                *(unsigned int*)((u16*)outv + so) = pk_bf16(h0, h1);
            } else {
                *(float2*)((float*)outv + so) = make_float2(h0, h1);
            }
        }
    }
    if (ck == NC - 1)
        *(float2*)(nh + (size_t)b * 512 + 2 * tid) = make_float2(h0, h1);
}

// ---------------------------------------------------------------------------
extern "C" void kernel_launch(void* const* d_in, const int* in_sizes, int n_in,
                              void* d_out, int out_size, void* d_ws, size_t ws_size,
                              hipStream_t stream)
{
    const float* x  = (const float*)d_in[0];
    const float* w0 = (const float*)d_in[1];
    const float* b0 = (const float*)d_in[2];
    const float* w1 = (const float*)d_in[3];
    const float* b1 = (const float*)d_in[4];
    float* out = (float*)d_out;

    const int B = 8, S = 4096, K = 512;
    const int M = B * S;             // 32768
    const int Lc = 32, Nc = S / Lc;  // 128 chunks of 32

    // workspace (bf16 elems): gh M*1024, xb M*512 (h0b aliases xb: xb is dead
    // after gemm0, which completes before pass3-L0 writes h0b), w0b/w1b.
    u16* gh  = (u16*)d_ws;
    u16* xb  = gh  + (size_t)M * 1024;
    u16* h0b = xb;                       // alias (stream-ordered safe)
    u16* w0b = xb  + (size_t)M * 512;
    u16* w1b = w0b + (size_t)1024 * 512;
    float* cA  = (float*)(w1b + (size_t)1024 * 512);
    float* cV  = cA  + (size_t)B * Nc * 512;
    float* cBA = cV  + (size_t)B * Nc * 512;
    float* cBV = cBA + (size_t)B * 32 * 512;

    float* nh0 = out + (size_t)M * 512;
    float* nh1 = nh0 + (size_t)B * 512;

    dim3 blk(256);
    dim3 ggrid(8, M / 128);          // 8 channel-blocks x 256 row-blocks
    dim3 sgrid(B * Nc);              // 1024

    const int nx4 = M * K / 4;           // 4,194,304
    const int nw4 = 1024 * K / 4;        // 131,072
    cast3<<<dim3((nx4 + 2 * nw4 + 255) / 256), blk, 0, stream>>>(
        x, xb, nx4, w0, w0b, w1, w1b, nw4);

    // ---- layer 0 ----
    gemm_fused<<<ggrid, blk, 0, stream>>>(xb, w0b, b0, gh, cA, cV, cBA, cBV, K);
    scan_pass3<true><<<sgrid, blk, 0, stream>>>(
        gh, cA, cV, cBA, cBV, h0b, nh0);

    // ---- layer 1 ----
    gemm_fused<<<ggrid, blk, 0, stream>>>(h0b, w1b, b1, gh, cA, cV, cBA, cBV, K);
    scan_pass3<false><<<sgrid, blk, 0, stream>>>(
        gh, cA, cV, cBA, cBV, out, nh1);
}